// Round 4
// baseline (360.368 us; speedup 1.0000x reference)
//
#include <hip/hip_runtime.h>
#include <cstddef>

#define BB 4
#define CC 512
#define NN 4096

using half8  = __attribute__((ext_vector_type(8))) _Float16;
using half4  = __attribute__((ext_vector_type(4))) _Float16;
using short8 = __attribute__((ext_vector_type(8))) short;
using f32x4  = __attribute__((ext_vector_type(4))) float;

__device__ __forceinline__ unsigned short f2bf(float x) {
    unsigned int u = __float_as_uint(x);
    u += 0x7fffu + ((u >> 16) & 1u);
    return (unsigned short)(u >> 16);
}

// ---------------- Kernel 0: weight conversion to fp16 ----------------
__global__ __launch_bounds__(256) void prep_kernel(
    const float* __restrict__ Wf, const float* __restrict__ Wg,
    const float* __restrict__ Wh, const float* __restrict__ Wv,
    _Float16* __restrict__ Wc16, _Float16* __restrict__ Wv16)
{
    int idx = blockIdx.x * 256 + threadIdx.x;
    int stride = gridDim.x * 256;
    const int N1 = 192 * 512, N2 = 512 * 64;
    for (int i = idx; i < N1 + N2; i += stride) {
        if (i < N1) {
            int row = i >> 9, c = i & 511;
            const float* src = (row < 64) ? Wf : ((row < 128) ? Wg : Wh);
            Wc16[i] = (_Float16)src[(row & 63) * 512 + c];
        } else {
            int k = i - N1;
            Wv16[k] = (_Float16)Wv[k];
        }
    }
}

// ---------------- Kernel 1: projections f,g,h via fp16 MFMA ----------------
// grid 1024: (b, i-chunk of 16).  Kf[b][i][64], Qf[b][i][64] fp16; Vt[b][d][4096] bf16
__global__ __launch_bounds__(256) void proj_kernel(
    const float* __restrict__ x, const _Float16* __restrict__ Wc16,
    _Float16* __restrict__ Kf, _Float16* __restrict__ Qf,
    unsigned short* __restrict__ Vt)
{
    const int t    = threadIdx.x;
    const int w    = t >> 6;
    const int lane = t & 63;
    const int lh   = lane & 15;
    const int qd   = lane >> 4;
    const int b    = blockIdx.x >> 8;
    const int i0   = (blockIdx.x & 255) << 4;

    f32x4 acc[3];
    #pragma unroll
    for (int ot = 0; ot < 3; ot++) { acc[ot][0]=0.f; acc[ot][1]=0.f; acc[ot][2]=0.f; acc[ot][3]=0.f; }

    const float* xb = x + (size_t)b*CC*NN + i0 + lh;
    const _Float16* wb = Wc16 + (size_t)(w*48 + lh)*512 + qd*8;

    for (int ck = 0; ck < 16; ck++) {
        half8 xf;
        const float* xp = xb + (size_t)(ck*32 + qd*8)*NN;
        #pragma unroll
        for (int jj = 0; jj < 8; jj++)
            xf[jj] = (_Float16)xp[(size_t)jj * NN];
        #pragma unroll
        for (int ot = 0; ot < 3; ot++) {
            half8 wf = *(const half8*)(wb + (size_t)(ot*16)*512 + ck*32);
            acc[ot] = __builtin_amdgcn_mfma_f32_16x16x32_f16(wf, xf, acc[ot], 0, 0, 0);
        }
    }

    #pragma unroll
    for (int ot = 0; ot < 3; ot++) {
        int g16 = w*3 + ot;
        int m   = g16 >> 2;
        int obase = (g16 & 3)*16 + qd*4;
        int ig = i0 + lh;
        #pragma unroll
        for (int r = 0; r < 4; r++) {
            float v = acc[ot][r];
            int ol = obase + r;
            if (m == 0)       Kf[((size_t)b*NN + ig)*64 + ol] = (_Float16)v;
            else if (m == 1)  Qf[((size_t)b*NN + ig)*64 + ol] = (_Float16)v;
            else              Vt[((size_t)b*64 + ol)*NN + ig] = f2bf(v);
        }
    }
}

// ---------------- Kernel 2: split-K MFMA flash attention ----------------
// grid 1024: (b, j-tile, split s of 16 key-tiles). Writes normalized partial
// Po16[s][b][j][64] (fp16) and weight Pl[s][b][j] (fp32).
__global__ __launch_bounds__(256, 4) void attn_kernel(
    const _Float16* __restrict__ Kf, const _Float16* __restrict__ Qf,
    const unsigned short* __restrict__ Vt,
    _Float16* __restrict__ Po16, float* __restrict__ Pl)
{
    __shared__ float Ps[4][16][68];   // per-wave private P tile [j_local][i]
    const int t    = threadIdx.x;
    const int wv   = t >> 6;
    const int lane = t & 63;
    const int lh   = lane & 15;
    const int qd   = lane >> 4;

    // XCD-aware swizzle: batch b pinned to XCD pair {2b,2b+1}
    const int B   = blockIdx.x;
    const int xcd = B & 7;
    const int rr  = B >> 3;               // 0..127
    const int b   = xcd >> 1;
    const int jt  = (rr & 31)*2 + (xcd & 1);
    const int s   = rr >> 5;              // key split 0..3
    const int j0  = (jt << 6) + wv*16;

    const size_t qb = ((size_t)b*NN + j0 + lh)*64 + qd*8;
    half8 qf[2];
    qf[0] = *(const half8*)(Qf + qb);
    qf[1] = *(const half8*)(Qf + qb + 32);

    f32x4 o_acc[4];
    float l_r[4];
    #pragma unroll
    for (int dt = 0; dt < 4; dt++) { o_acc[dt][0]=0.f; o_acc[dt][1]=0.f; o_acc[dt][2]=0.f; o_acc[dt][3]=0.f; }
    #pragma unroll
    for (int r = 0; r < 4; r++) l_r[r] = 0.f;

    const size_t kroot = ((size_t)b*NN + lh)*64 + qd*8;   // + kt*4096 + it*1024 + ks*32
    const size_t vroot = ((size_t)b*64 + lh)*NN + qd*8;   // + kt*64 + dt*65536 + ks*32
    const int s16 = s*16;

#define LOADKV(KF, VF, kt) do {                                              \
    size_t kb_ = kroot + (size_t)(kt)*4096;                                  \
    size_t vb_ = vroot + (size_t)(kt)*64;                                    \
    _Pragma("unroll")                                                        \
    for (int it_ = 0; it_ < 4; it_++) {                                      \
        _Pragma("unroll")                                                    \
        for (int ks_ = 0; ks_ < 2; ks_++)                                    \
            KF[it_][ks_] = *(const half8*)(Kf + kb_ + it_*1024 + ks_*32);    \
    }                                                                        \
    _Pragma("unroll")                                                        \
    for (int dt_ = 0; dt_ < 4; dt_++) {                                      \
        _Pragma("unroll")                                                    \
        for (int ks_ = 0; ks_ < 2; ks_++)                                    \
            VF[dt_][ks_] = *(const short8*)(Vt + vb_ + dt_*65536 + ks_*32);  \
    } } while (0)

#define COMPUTE(KF, VF) do {                                                 \
    f32x4 s_[4];                                                             \
    _Pragma("unroll")                                                        \
    for (int it_ = 0; it_ < 4; it_++) {                                      \
        s_[it_][0]=0.f; s_[it_][1]=0.f; s_[it_][2]=0.f; s_[it_][3]=0.f;      \
        s_[it_] = __builtin_amdgcn_mfma_f32_16x16x32_f16(qf[0], KF[it_][0], s_[it_], 0,0,0); \
        s_[it_] = __builtin_amdgcn_mfma_f32_16x16x32_f16(qf[1], KF[it_][1], s_[it_], 0,0,0); \
    }                                                                        \
    _Pragma("unroll")                                                        \
    for (int it_ = 0; it_ < 4; it_++)                                        \
        _Pragma("unroll")                                                    \
        for (int r_ = 0; r_ < 4; r_++) {                                     \
            float p_ = __expf(s_[it_][r_]);                                  \
            l_r[r_] += p_;                                                   \
            Ps[wv][qd*4 + r_][it_*16 + lh] = p_;                             \
        }                                                                    \
    asm volatile("s_waitcnt lgkmcnt(0)" ::: "memory");                       \
    short8 pf_[2];                                                           \
    _Pragma("unroll")                                                        \
    for (int ks_ = 0; ks_ < 2; ks_++) {                                      \
        const float* pp_ = &Ps[wv][lh][ks_*32 + qd*8];                       \
        f32x4 x0_ = *(const f32x4*)pp_;                                      \
        f32x4 x1_ = *(const f32x4*)(pp_ + 4);                                \
        pf_[ks_][0] = (short)f2bf(x0_[0]); pf_[ks_][1] = (short)f2bf(x0_[1]);\
        pf_[ks_][2] = (short)f2bf(x0_[2]); pf_[ks_][3] = (short)f2bf(x0_[3]);\
        pf_[ks_][4] = (short)f2bf(x1_[0]); pf_[ks_][5] = (short)f2bf(x1_[1]);\
        pf_[ks_][6] = (short)f2bf(x1_[2]); pf_[ks_][7] = (short)f2bf(x1_[3]);\
    }                                                                        \
    _Pragma("unroll")                                                        \
    for (int dt_ = 0; dt_ < 4; dt_++) {                                      \
        o_acc[dt_] = __builtin_amdgcn_mfma_f32_16x16x32_bf16(pf_[0], VF[dt_][0], o_acc[dt_], 0,0,0); \
        o_acc[dt_] = __builtin_amdgcn_mfma_f32_16x16x32_bf16(pf_[1], VF[dt_][1], o_acc[dt_], 0,0,0); \
    } } while (0)

    half8  kfA[4][2], kfB[4][2];
    short8 vfA[4][2], vfB[4][2];
    LOADKV(kfA, vfA, s16);
    for (int lt = 0; lt < 16; lt += 2) {
        LOADKV(kfB, vfB, s16 + lt + 1);
        COMPUTE(kfA, vfA);
        if (lt + 2 < 16) LOADKV(kfA, vfA, s16 + lt + 2);
        COMPUTE(kfB, vfB);
    }
#undef LOADKV
#undef COMPUTE

    // reduce l over the 16 lh-lanes sharing each j-row
    float inv[4];
    #pragma unroll
    for (int r = 0; r < 4; r++) {
        float l = l_r[r];
        #pragma unroll
        for (int off = 1; off < 16; off <<= 1)
            l += __shfl_xor(l, off);
        l_r[r] = l;
        inv[r] = 1.0f / l;
    }
    const size_t pbase = ((size_t)(s*4 + b)*NN + j0);
    #pragma unroll
    for (int dt = 0; dt < 4; dt++)
        #pragma unroll
        for (int r = 0; r < 4; r++)
            Po16[(pbase + qd*4 + r)*64 + dt*16 + lh] = (_Float16)(o_acc[dt][r] * inv[r]);
    if (lh == 0) {
        #pragma unroll
        for (int r = 0; r < 4; r++)
            Pl[pbase + qd*4 + r] = l_r[r];
    }
}

// ---------------- Kernel 3: combine split-K partials -> sa16 ----------------
__global__ __launch_bounds__(256) void combine_kernel(
    const _Float16* __restrict__ Po16, const float* __restrict__ Pl,
    _Float16* __restrict__ sa16)
{
    int tid = blockIdx.x * 256 + threadIdx.x;    // 262144 threads
    int d4  = (tid & 15) * 4;
    int j   = (tid >> 4) & 4095;
    int b   = tid >> 16;
    float o0 = 0.f, o1 = 0.f, o2 = 0.f, o3 = 0.f, lsum = 0.f;
    #pragma unroll
    for (int s = 0; s < 4; s++) {
        size_t base = ((size_t)(s*4 + b)*NN + j);
        half4 v = *(const half4*)(Po16 + base*64 + d4);
        float l = Pl[base];
        o0 += l * (float)v[0]; o1 += l * (float)v[1];
        o2 += l * (float)v[2]; o3 += l * (float)v[3];
        lsum += l;
    }
    float inv = 1.0f / lsum;
    half4 r;
    r[0] = (_Float16)(o0 * inv); r[1] = (_Float16)(o1 * inv);
    r[2] = (_Float16)(o2 * inv); r[3] = (_Float16)(o3 * inv);
    *(half4*)(sa16 + ((size_t)b*NN + j)*64 + d4) = r;
}

// ---------------- Kernel 4: output projection + residual ----------------
// grid 512: (b, j-chunk of 32)
__global__ __launch_bounds__(256) void outproj_kernel(
    const _Float16* __restrict__ sa16, const _Float16* __restrict__ Wv16,
    const float* __restrict__ x, const float* __restrict__ gamma,
    float* __restrict__ out1, float* __restrict__ out2)
{
    const int t    = threadIdx.x;
    const int w    = t >> 6;
    const int lane = t & 63;
    const int lh   = lane & 15;
    const int qd   = lane >> 4;
    const int b    = blockIdx.x >> 7;
    const int j0   = (blockIdx.x & 127) << 5;
    const float g  = gamma[0];

    half8 sb[2][2];
    #pragma unroll
    for (int jt2 = 0; jt2 < 2; jt2++) {
        const size_t sbase = ((size_t)b*NN + j0 + jt2*16 + lh)*64 + qd*8;
        sb[jt2][0] = *(const half8*)(sa16 + sbase);
        sb[jt2][1] = *(const half8*)(sa16 + sbase + 32);
    }

    #pragma unroll 2
    for (int ot8 = 0; ot8 < 8; ot8++) {
        const int ot = w*8 + ot8;
        const size_t wbase = (size_t)(ot*16 + lh)*64 + qd*8;
        half8 a0 = *(const half8*)(Wv16 + wbase);
        half8 a1 = *(const half8*)(Wv16 + wbase + 32);
        #pragma unroll
        for (int jt2 = 0; jt2 < 2; jt2++) {
            f32x4 acc; acc[0]=0.f; acc[1]=0.f; acc[2]=0.f; acc[3]=0.f;
            acc = __builtin_amdgcn_mfma_f32_16x16x32_f16(a0, sb[jt2][0], acc, 0, 0, 0);
            acc = __builtin_amdgcn_mfma_f32_16x16x32_f16(a1, sb[jt2][1], acc, 0, 0, 0);
            const int jg = j0 + jt2*16 + lh;
            #pragma unroll
            for (int r = 0; r < 4; r++) {
                const int o = ot*16 + qd*4 + r;
                size_t idx = ((size_t)b*CC + o)*NN + jg;
                float v = acc[r];
                out2[idx] = v;
                out1[idx] = fmaf(g, v, x[idx]);
            }
        }
    }
}

extern "C" void kernel_launch(void* const* d_in, const int* in_sizes, int n_in,
                              void* d_out, int out_size, void* d_ws, size_t ws_size,
                              hipStream_t stream) {
    const float* x     = (const float*)d_in[0];
    const float* Wf    = (const float*)d_in[1];
    const float* Wg    = (const float*)d_in[2];
    const float* Wh    = (const float*)d_in[3];
    const float* Wv    = (const float*)d_in[4];
    const float* gamma = (const float*)d_in[5];

    float* out1 = (float*)d_out;
    float* out2 = out1 + (size_t)BB*CC*NN;

    const size_t BND = (size_t)BB*NN*64;   // 1M elements
    char* wp = (char*)d_ws;
    _Float16*       Kf   = (_Float16*)wp;        wp += BND*2;   // 2 MB (reused as sa16)
    _Float16*       Qf   = (_Float16*)wp;        wp += BND*2;   // 2 MB
    unsigned short* Vt   = (unsigned short*)wp;  wp += BND*2;   // 2 MB
    _Float16*       Po16 = (_Float16*)wp;        wp += BND*4*2; // 8 MB (4 splits)
    float*          Pl   = (float*)wp;           wp += (size_t)4*BB*NN*4;  // 256 KB
    _Float16*       Wc16 = (_Float16*)wp;        wp += (size_t)192*512*2;
    _Float16*       Wv16 = (_Float16*)wp;
    _Float16*       sa16 = Kf;   // alias: Kf dead after attn

    prep_kernel<<<dim3(64), dim3(256), 0, stream>>>(Wf, Wg, Wh, Wv, Wc16, Wv16);
    proj_kernel<<<dim3(BB*256), dim3(256), 0, stream>>>(x, Wc16, Kf, Qf, Vt);
    attn_kernel<<<dim3(BB*256), dim3(256), 0, stream>>>(Kf, Qf, Vt, Po16, Pl);
    combine_kernel<<<dim3(1024), dim3(256), 0, stream>>>(Po16, Pl, sa16);
    outproj_kernel<<<dim3(512), dim3(256), 0, stream>>>(sa16, Wv16, x, gamma, out1, out2);
}

// Round 5
// 260.060 us; speedup vs baseline: 1.3857x; 1.3857x over previous
//
#include <hip/hip_runtime.h>
#include <cstddef>

#define BB 4
#define CC 512
#define NN 4096

using half8  = __attribute__((ext_vector_type(8))) _Float16;
using half4  = __attribute__((ext_vector_type(4))) _Float16;
using short8 = __attribute__((ext_vector_type(8))) short;
using f32x4  = __attribute__((ext_vector_type(4))) float;

__device__ __forceinline__ unsigned short f2bf(float x) {
    unsigned int u = __float_as_uint(x);
    u += 0x7fffu + ((u >> 16) & 1u);
    return (unsigned short)(u >> 16);
}

// ---------------- Kernel 0: weight conversion to fp16 ----------------
__global__ __launch_bounds__(256) void prep_kernel(
    const float* __restrict__ Wf, const float* __restrict__ Wg,
    const float* __restrict__ Wh, const float* __restrict__ Wv,
    _Float16* __restrict__ Wc16, _Float16* __restrict__ Wv16)
{
    int idx = blockIdx.x * 256 + threadIdx.x;
    int stride = gridDim.x * 256;
    const int N1 = 192 * 512, N2 = 512 * 64;
    for (int i = idx; i < N1 + N2; i += stride) {
        if (i < N1) {
            int row = i >> 9, c = i & 511;
            const float* src = (row < 64) ? Wf : ((row < 128) ? Wg : Wh);
            Wc16[i] = (_Float16)src[(row & 63) * 512 + c];
        } else {
            int k = i - N1;
            Wv16[k] = (_Float16)Wv[k];
        }
    }
}

// ---------------- Kernel 1: projections f,g,h via fp16 MFMA ----------------
// grid 1024: (b, i-chunk of 16).  Kf[b][i][64], Qf[b][i][64] fp16; Vt[b][d][4096] bf16
__global__ __launch_bounds__(256) void proj_kernel(
    const float* __restrict__ x, const _Float16* __restrict__ Wc16,
    _Float16* __restrict__ Kf, _Float16* __restrict__ Qf,
    unsigned short* __restrict__ Vt)
{
    const int t    = threadIdx.x;
    const int w    = t >> 6;
    const int lane = t & 63;
    const int lh   = lane & 15;
    const int qd   = lane >> 4;
    const int b    = blockIdx.x >> 8;
    const int i0   = (blockIdx.x & 255) << 4;

    f32x4 acc[3];
    #pragma unroll
    for (int ot = 0; ot < 3; ot++) { acc[ot][0]=0.f; acc[ot][1]=0.f; acc[ot][2]=0.f; acc[ot][3]=0.f; }

    const float* xb = x + (size_t)b*CC*NN + i0 + lh;
    const _Float16* wb = Wc16 + (size_t)(w*48 + lh)*512 + qd*8;

    for (int ck = 0; ck < 16; ck++) {
        half8 xf;
        const float* xp = xb + (size_t)(ck*32 + qd*8)*NN;
        #pragma unroll
        for (int jj = 0; jj < 8; jj++)
            xf[jj] = (_Float16)xp[(size_t)jj * NN];
        #pragma unroll
        for (int ot = 0; ot < 3; ot++) {
            half8 wf = *(const half8*)(wb + (size_t)(ot*16)*512 + ck*32);
            acc[ot] = __builtin_amdgcn_mfma_f32_16x16x32_f16(wf, xf, acc[ot], 0, 0, 0);
        }
    }

    #pragma unroll
    for (int ot = 0; ot < 3; ot++) {
        int g16 = w*3 + ot;
        int m   = g16 >> 2;
        int obase = (g16 & 3)*16 + qd*4;
        int ig = i0 + lh;
        #pragma unroll
        for (int r = 0; r < 4; r++) {
            float v = acc[ot][r];
            int ol = obase + r;
            if (m == 0)       Kf[((size_t)b*NN + ig)*64 + ol] = (_Float16)v;
            else if (m == 1)  Qf[((size_t)b*NN + ig)*64 + ol] = (_Float16)v;
            else              Vt[((size_t)b*64 + ol)*NN + ig] = f2bf(v);
        }
    }
}

// ---------------- Kernel 2: split-K MFMA flash attention ----------------
// grid 1024: (b, j-tile, split s of 16 key-tiles). Writes normalized partial
// Po16[s][b][j][64] (fp16) and weight Pl[s][b][j] (fp32).
// NOTE: __launch_bounds__(256,1) — (256,4) capped VGPRs at 64 and caused
// ~880 MB of scratch spill traffic (R4). 116 VGPRs still allows 4 waves/SIMD.
__global__ __launch_bounds__(256, 1) void attn_kernel(
    const _Float16* __restrict__ Kf, const _Float16* __restrict__ Qf,
    const unsigned short* __restrict__ Vt,
    _Float16* __restrict__ Po16, float* __restrict__ Pl)
{
    __shared__ float Ps[4][16][68];   // per-wave private P tile [j_local][i]
    const int t    = threadIdx.x;
    const int wv   = t >> 6;
    const int lane = t & 63;
    const int lh   = lane & 15;
    const int qd   = lane >> 4;

    // XCD-aware swizzle: batch b pinned to XCD pair {2b,2b+1}
    const int B   = blockIdx.x;
    const int xcd = B & 7;
    const int rr  = B >> 3;               // 0..127
    const int b   = xcd >> 1;
    const int jt  = (rr & 31)*2 + (xcd & 1);
    const int s   = rr >> 5;              // key split 0..3
    const int j0  = (jt << 6) + wv*16;

    const size_t qb = ((size_t)b*NN + j0 + lh)*64 + qd*8;
    half8 qf[2];
    qf[0] = *(const half8*)(Qf + qb);
    qf[1] = *(const half8*)(Qf + qb + 32);

    f32x4 o_acc[4];
    float l_r[4];
    #pragma unroll
    for (int dt = 0; dt < 4; dt++) { o_acc[dt][0]=0.f; o_acc[dt][1]=0.f; o_acc[dt][2]=0.f; o_acc[dt][3]=0.f; }
    #pragma unroll
    for (int r = 0; r < 4; r++) l_r[r] = 0.f;

    const size_t kroot = ((size_t)b*NN + lh)*64 + qd*8;   // + kt*4096 + it*1024 + ks*32
    const size_t vroot = ((size_t)b*64 + lh)*NN + qd*8;   // + kt*64 + dt*65536 + ks*32
    const int s16 = s*16;

#define LOADKV(KF, VF, kt) do {                                              \
    size_t kb_ = kroot + (size_t)(kt)*4096;                                  \
    size_t vb_ = vroot + (size_t)(kt)*64;                                    \
    _Pragma("unroll")                                                        \
    for (int it_ = 0; it_ < 4; it_++) {                                      \
        _Pragma("unroll")                                                    \
        for (int ks_ = 0; ks_ < 2; ks_++)                                    \
            KF[it_][ks_] = *(const half8*)(Kf + kb_ + it_*1024 + ks_*32);    \
    }                                                                        \
    _Pragma("unroll")                                                        \
    for (int dt_ = 0; dt_ < 4; dt_++) {                                      \
        _Pragma("unroll")                                                    \
        for (int ks_ = 0; ks_ < 2; ks_++)                                    \
            VF[dt_][ks_] = *(const short8*)(Vt + vb_ + dt_*65536 + ks_*32);  \
    } } while (0)

#define COMPUTE(KF, VF) do {                                                 \
    f32x4 s_[4];                                                             \
    _Pragma("unroll")                                                        \
    for (int it_ = 0; it_ < 4; it_++) {                                      \
        s_[it_][0]=0.f; s_[it_][1]=0.f; s_[it_][2]=0.f; s_[it_][3]=0.f;      \
        s_[it_] = __builtin_amdgcn_mfma_f32_16x16x32_f16(qf[0], KF[it_][0], s_[it_], 0,0,0); \
        s_[it_] = __builtin_amdgcn_mfma_f32_16x16x32_f16(qf[1], KF[it_][1], s_[it_], 0,0,0); \
    }                                                                        \
    _Pragma("unroll")                                                        \
    for (int it_ = 0; it_ < 4; it_++)                                        \
        _Pragma("unroll")                                                    \
        for (int r_ = 0; r_ < 4; r_++) {                                     \
            float p_ = __expf(s_[it_][r_]);                                  \
            l_r[r_] += p_;                                                   \
            Ps[wv][qd*4 + r_][it_*16 + lh] = p_;                             \
        }                                                                    \
    asm volatile("s_waitcnt lgkmcnt(0)" ::: "memory");                       \
    short8 pf_[2];                                                           \
    _Pragma("unroll")                                                        \
    for (int ks_ = 0; ks_ < 2; ks_++) {                                      \
        const float* pp_ = &Ps[wv][lh][ks_*32 + qd*8];                       \
        f32x4 x0_ = *(const f32x4*)pp_;                                      \
        f32x4 x1_ = *(const f32x4*)(pp_ + 4);                                \
        pf_[ks_][0] = (short)f2bf(x0_[0]); pf_[ks_][1] = (short)f2bf(x0_[1]);\
        pf_[ks_][2] = (short)f2bf(x0_[2]); pf_[ks_][3] = (short)f2bf(x0_[3]);\
        pf_[ks_][4] = (short)f2bf(x1_[0]); pf_[ks_][5] = (short)f2bf(x1_[1]);\
        pf_[ks_][6] = (short)f2bf(x1_[2]); pf_[ks_][7] = (short)f2bf(x1_[3]);\
    }                                                                        \
    _Pragma("unroll")                                                        \
    for (int dt_ = 0; dt_ < 4; dt_++) {                                      \
        o_acc[dt_] = __builtin_amdgcn_mfma_f32_16x16x32_bf16(pf_[0], VF[dt_][0], o_acc[dt_], 0,0,0); \
        o_acc[dt_] = __builtin_amdgcn_mfma_f32_16x16x32_bf16(pf_[1], VF[dt_][1], o_acc[dt_], 0,0,0); \
    } } while (0)

    half8  kfA[4][2], kfB[4][2];
    short8 vfA[4][2], vfB[4][2];
    LOADKV(kfA, vfA, s16);
    for (int lt = 0; lt < 16; lt += 2) {
        LOADKV(kfB, vfB, s16 + lt + 1);
        COMPUTE(kfA, vfA);
        if (lt + 2 < 16) LOADKV(kfA, vfA, s16 + lt + 2);
        COMPUTE(kfB, vfB);
    }
#undef LOADKV
#undef COMPUTE

    // reduce l over the 16 lh-lanes sharing each j-row
    float inv[4];
    #pragma unroll
    for (int r = 0; r < 4; r++) {
        float l = l_r[r];
        #pragma unroll
        for (int off = 1; off < 16; off <<= 1)
            l += __shfl_xor(l, off);
        l_r[r] = l;
        inv[r] = 1.0f / l;
    }
    const size_t pbase = ((size_t)(s*4 + b)*NN + j0);
    #pragma unroll
    for (int dt = 0; dt < 4; dt++)
        #pragma unroll
        for (int r = 0; r < 4; r++)
            Po16[(pbase + qd*4 + r)*64 + dt*16 + lh] = (_Float16)(o_acc[dt][r] * inv[r]);
    if (lh == 0) {
        #pragma unroll
        for (int r = 0; r < 4; r++)
            Pl[pbase + qd*4 + r] = l_r[r];
    }
}

// ---------------- Kernel 3: combine split-K partials -> sa16 ----------------
__global__ __launch_bounds__(256) void combine_kernel(
    const _Float16* __restrict__ Po16, const float* __restrict__ Pl,
    _Float16* __restrict__ sa16)
{
    int tid = blockIdx.x * 256 + threadIdx.x;    // 262144 threads
    int d4  = (tid & 15) * 4;
    int j   = (tid >> 4) & 4095;
    int b   = tid >> 16;
    float o0 = 0.f, o1 = 0.f, o2 = 0.f, o3 = 0.f, lsum = 0.f;
    #pragma unroll
    for (int s = 0; s < 4; s++) {
        size_t base = ((size_t)(s*4 + b)*NN + j);
        half4 v = *(const half4*)(Po16 + base*64 + d4);
        float l = Pl[base];
        o0 += l * (float)v[0]; o1 += l * (float)v[1];
        o2 += l * (float)v[2]; o3 += l * (float)v[3];
        lsum += l;
    }
    float inv = 1.0f / lsum;
    half4 r;
    r[0] = (_Float16)(o0 * inv); r[1] = (_Float16)(o1 * inv);
    r[2] = (_Float16)(o2 * inv); r[3] = (_Float16)(o3 * inv);
    *(half4*)(sa16 + ((size_t)b*NN + j)*64 + d4) = r;
}

// ---------------- Kernel 4: output projection + residual ----------------
// grid 512: (b, j-chunk of 32)
__global__ __launch_bounds__(256) void outproj_kernel(
    const _Float16* __restrict__ sa16, const _Float16* __restrict__ Wv16,
    const float* __restrict__ x, const float* __restrict__ gamma,
    float* __restrict__ out1, float* __restrict__ out2)
{
    const int t    = threadIdx.x;
    const int w    = t >> 6;
    const int lane = t & 63;
    const int lh   = lane & 15;
    const int qd   = lane >> 4;
    const int b    = blockIdx.x >> 7;
    const int j0   = (blockIdx.x & 127) << 5;
    const float g  = gamma[0];

    half8 sb[2][2];
    #pragma unroll
    for (int jt2 = 0; jt2 < 2; jt2++) {
        const size_t sbase = ((size_t)b*NN + j0 + jt2*16 + lh)*64 + qd*8;
        sb[jt2][0] = *(const half8*)(sa16 + sbase);
        sb[jt2][1] = *(const half8*)(sa16 + sbase + 32);
    }

    #pragma unroll 2
    for (int ot8 = 0; ot8 < 8; ot8++) {
        const int ot = w*8 + ot8;
        const size_t wbase = (size_t)(ot*16 + lh)*64 + qd*8;
        half8 a0 = *(const half8*)(Wv16 + wbase);
        half8 a1 = *(const half8*)(Wv16 + wbase + 32);
        #pragma unroll
        for (int jt2 = 0; jt2 < 2; jt2++) {
            f32x4 acc; acc[0]=0.f; acc[1]=0.f; acc[2]=0.f; acc[3]=0.f;
            acc = __builtin_amdgcn_mfma_f32_16x16x32_f16(a0, sb[jt2][0], acc, 0, 0, 0);
            acc = __builtin_amdgcn_mfma_f32_16x16x32_f16(a1, sb[jt2][1], acc, 0, 0, 0);
            const int jg = j0 + jt2*16 + lh;
            #pragma unroll
            for (int r = 0; r < 4; r++) {
                const int o = ot*16 + qd*4 + r;
                size_t idx = ((size_t)b*CC + o)*NN + jg;
                float v = acc[r];
                out2[idx] = v;
                out1[idx] = fmaf(g, v, x[idx]);
            }
        }
    }
}

extern "C" void kernel_launch(void* const* d_in, const int* in_sizes, int n_in,
                              void* d_out, int out_size, void* d_ws, size_t ws_size,
                              hipStream_t stream) {
    const float* x     = (const float*)d_in[0];
    const float* Wf    = (const float*)d_in[1];
    const float* Wg    = (const float*)d_in[2];
    const float* Wh    = (const float*)d_in[3];
    const float* Wv    = (const float*)d_in[4];
    const float* gamma = (const float*)d_in[5];

    float* out1 = (float*)d_out;
    float* out2 = out1 + (size_t)BB*CC*NN;

    const size_t BND = (size_t)BB*NN*64;   // 1M elements
    char* wp = (char*)d_ws;
    _Float16*       Kf   = (_Float16*)wp;        wp += BND*2;   // 2 MB (reused as sa16)
    _Float16*       Qf   = (_Float16*)wp;        wp += BND*2;   // 2 MB
    unsigned short* Vt   = (unsigned short*)wp;  wp += BND*2;   // 2 MB
    _Float16*       Po16 = (_Float16*)wp;        wp += BND*4*2; // 8 MB (4 splits)
    float*          Pl   = (float*)wp;           wp += (size_t)4*BB*NN*4;  // 256 KB
    _Float16*       Wc16 = (_Float16*)wp;        wp += (size_t)192*512*2;
    _Float16*       Wv16 = (_Float16*)wp;
    _Float16*       sa16 = Kf;   // alias: Kf dead after attn

    prep_kernel<<<dim3(64), dim3(256), 0, stream>>>(Wf, Wg, Wh, Wv, Wc16, Wv16);
    proj_kernel<<<dim3(BB*256), dim3(256), 0, stream>>>(x, Wc16, Kf, Qf, Vt);
    attn_kernel<<<dim3(BB*256), dim3(256), 0, stream>>>(Kf, Qf, Vt, Po16, Pl);
    combine_kernel<<<dim3(1024), dim3(256), 0, stream>>>(Po16, Pl, sa16);
    outproj_kernel<<<dim3(512), dim3(256), 0, stream>>>(sa16, Wv16, x, gamma, out1, out2);
}

// Round 6
// 183.684 us; speedup vs baseline: 1.9619x; 1.4158x over previous
//
#include <hip/hip_runtime.h>
#include <cstddef>

#define BB 4
#define CC 512
#define NN 4096

using half8  = __attribute__((ext_vector_type(8))) _Float16;
using half4  = __attribute__((ext_vector_type(4))) _Float16;
using short8 = __attribute__((ext_vector_type(8))) short;
using us8    = __attribute__((ext_vector_type(8))) unsigned short;
using f32x4  = __attribute__((ext_vector_type(4))) float;

__device__ __forceinline__ unsigned short f2bf(float x) {
    unsigned int u = __float_as_uint(x);
    u += 0x7fffu + ((u >> 16) & 1u);
    return (unsigned short)(u >> 16);
}

// ---------------- Kernel 0: weight conversion to fp16 ----------------
__global__ __launch_bounds__(256) void prep_kernel(
    const float* __restrict__ Wf, const float* __restrict__ Wg,
    const float* __restrict__ Wh, const float* __restrict__ Wv,
    _Float16* __restrict__ Wc16, _Float16* __restrict__ Wv16)
{
    int idx = blockIdx.x * 256 + threadIdx.x;
    int stride = gridDim.x * 256;
    const int N1 = 192 * 512, N2 = 512 * 64;
    for (int i = idx; i < N1 + N2; i += stride) {
        if (i < N1) {
            int row = i >> 9, c = i & 511;
            const float* src = (row < 64) ? Wf : ((row < 128) ? Wg : Wh);
            Wc16[i] = (_Float16)src[(row & 63) * 512 + c];
        } else {
            int k = i - N1;
            Wv16[k] = (_Float16)Wv[k];
        }
    }
}

// ---------------- Kernel 1: projections f,g,h via fp16 MFMA ----------------
// grid 1024: (b, i-chunk of 16).  Kf[b][i][64], Qf[b][i][64] fp16; Vt[b][d][4096] bf16
__global__ __launch_bounds__(256) void proj_kernel(
    const float* __restrict__ x, const _Float16* __restrict__ Wc16,
    _Float16* __restrict__ Kf, _Float16* __restrict__ Qf,
    unsigned short* __restrict__ Vt)
{
    const int t    = threadIdx.x;
    const int w    = t >> 6;
    const int lane = t & 63;
    const int lh   = lane & 15;
    const int qd   = lane >> 4;
    const int b    = blockIdx.x >> 8;
    const int i0   = (blockIdx.x & 255) << 4;

    f32x4 acc[3];
    #pragma unroll
    for (int ot = 0; ot < 3; ot++) { acc[ot][0]=0.f; acc[ot][1]=0.f; acc[ot][2]=0.f; acc[ot][3]=0.f; }

    const float* xb = x + (size_t)b*CC*NN + i0 + lh;
    const _Float16* wb = Wc16 + (size_t)(w*48 + lh)*512 + qd*8;

    for (int ck = 0; ck < 16; ck++) {
        half8 xf;
        const float* xp = xb + (size_t)(ck*32 + qd*8)*NN;
        #pragma unroll
        for (int jj = 0; jj < 8; jj++)
            xf[jj] = (_Float16)xp[(size_t)jj * NN];
        #pragma unroll
        for (int ot = 0; ot < 3; ot++) {
            half8 wf = *(const half8*)(wb + (size_t)(ot*16)*512 + ck*32);
            acc[ot] = __builtin_amdgcn_mfma_f32_16x16x32_f16(wf, xf, acc[ot], 0, 0, 0);
        }
    }

    #pragma unroll
    for (int ot = 0; ot < 3; ot++) {
        int g16 = w*3 + ot;
        int m   = g16 >> 2;
        int obase = (g16 & 3)*16 + qd*4;
        int ig = i0 + lh;
        #pragma unroll
        for (int r = 0; r < 4; r++) {
            float v = acc[ot][r];
            int ol = obase + r;
            if (m == 0)       Kf[((size_t)b*NN + ig)*64 + ol] = (_Float16)v;
            else if (m == 1)  Qf[((size_t)b*NN + ig)*64 + ol] = (_Float16)v;
            else              Vt[((size_t)b*64 + ol)*NN + ig] = f2bf(v);
        }
    }
}

// ---------------- Kernel 2: split-K flash attention, LDS-staged K/V ----------------
// grid 1024: (b, j-tile of 64, split s of 1024 keys = 8 chunks of 128).
// K/V chunks double-buffered in LDS with XOR-swizzled 16B blocks (conflict-free
// column frag reads). Chunk c+1 prefetched into registers during compute of c.
// Writes normalized partials Po16[s][b][j][64] (fp16) + weight Pl[s][b][j] (f32).
__global__ __launch_bounds__(256) void attn_kernel(
    const _Float16* __restrict__ Kf, const _Float16* __restrict__ Qf,
    const unsigned short* __restrict__ Vt,
    _Float16* __restrict__ Po16, float* __restrict__ Pl)
{
    __shared__ __align__(16) unsigned short Kbuf[2][128*64];  // [i][d] rows 128B, 16KB each
    __shared__ __align__(16) unsigned short Vbuf[2][64*128];  // [d][i] rows 256B, 16KB each
    __shared__ __align__(16) unsigned short Psh[4][16*64];    // per-wave P bf16, rows 128B

    const int t    = threadIdx.x;
    const int wv   = t >> 6;
    const int lane = t & 63;
    const int lh   = lane & 15;
    const int qd   = lane >> 4;

    // XCD-aware swizzle: batch b pinned to XCD pair {2b,2b+1}
    const int B   = blockIdx.x;
    const int xcd = B & 7;
    const int rr  = B >> 3;               // 0..127
    const int b   = xcd >> 1;
    const int jt  = (rr & 31)*2 + (xcd & 1);
    const int s   = rr >> 5;              // key split 0..3
    const int j0  = (jt << 6) + wv*16;

    const unsigned short* Kfu = (const unsigned short*)Kf;

    half8 qf0, qf1;
    {
        const size_t qb = ((size_t)b*NN + j0 + lh)*64 + qd*8;
        qf0 = *(const half8*)(Qf + qb);
        qf1 = *(const half8*)(Qf + qb + 32);
    }

    f32x4 o_acc[4];
    float l_r[4];
    #pragma unroll
    for (int dt = 0; dt < 4; dt++) { o_acc[dt][0]=0.f; o_acc[dt][1]=0.f; o_acc[dt][2]=0.f; o_acc[dt][3]=0.f; }
    #pragma unroll
    for (int r = 0; r < 4; r++) l_r[r] = 0.f;

    const int koff = s*1024;
    // staging decode (per thread, 4 rounds for K + 4 for V)
    const int ki = t >> 3, kc = t & 7;     // K: row i step 32/round, 16B chunk kc
    const int vd = t >> 4, vc = t & 15;    // V: row d step 16/round, 16B chunk vc

#define LOADC(ck) do {                                                        \
    size_t kg = ((size_t)b*NN + koff + (ck)*128)*64;                          \
    size_t vg = (size_t)b*64*NN + koff + (ck)*128;                            \
    _Pragma("unroll")                                                         \
    for (int r_ = 0; r_ < 4; r_++) {                                          \
        kst[r_] = *(const us8*)(Kfu + kg + (size_t)(r_*32 + ki)*64 + kc*8);   \
        vst[r_] = *(const us8*)(Vt  + vg + (size_t)(r_*16 + vd)*NN + vc*8);   \
    } } while (0)

#define STOREC(p_) do {                                                       \
    _Pragma("unroll")                                                         \
    for (int r_ = 0; r_ < 4; r_++) {                                          \
        int i_ = r_*32 + ki;                                                  \
        int d_ = r_*16 + vd;                                                  \
        *(us8*)(&Kbuf[p_][i_*64  + ((kc ^ (i_ & 7))*8)])  = kst[r_];          \
        *(us8*)(&Vbuf[p_][d_*128 + ((vc ^ (d_ & 15))*8)]) = vst[r_];          \
    } } while (0)

    us8 kst[4], vst[4];
    LOADC(0);
    STOREC(0);
    __syncthreads();

    for (int ck = 0; ck < 8; ck++) {
        const int p = ck & 1;
        if (ck < 7) LOADC(ck + 1);

        #pragma unroll
        for (int half = 0; half < 2; half++) {
            const unsigned short* Kb = &Kbuf[p][half*64*64];
            const unsigned short* Vb = &Vbuf[p][0];

            // S tile: S[j=qd*4+r][i=it*16+lh] over 64 keys
            f32x4 sc[4];
            #pragma unroll
            for (int it = 0; it < 4; it++) {
                sc[it][0]=0.f; sc[it][1]=0.f; sc[it][2]=0.f; sc[it][3]=0.f;
                const unsigned short* kr = Kb + (it*16 + lh)*64;
                half8 k0 = *(const half8*)(kr + ((qd     ^ (lh & 7))*8));
                half8 k1 = *(const half8*)(kr + (((4+qd) ^ (lh & 7))*8));
                sc[it] = __builtin_amdgcn_mfma_f32_16x16x32_f16(qf0, k0, sc[it], 0,0,0);
                sc[it] = __builtin_amdgcn_mfma_f32_16x16x32_f16(qf1, k1, sc[it], 0,0,0);
            }

            // exp + bf16 P write into per-wave swizzled LDS
            #pragma unroll
            for (int it = 0; it < 4; it++)
                #pragma unroll
                for (int r = 0; r < 4; r++) {
                    float p_ = __expf(sc[it][r]);
                    l_r[r] += p_;
                    int i_ = it*16 + lh;
                    int j_ = qd*4 + r;
                    Psh[wv][j_*64 + (((i_>>3) ^ (j_ & 7))*8) + (i_ & 7)] = f2bf(p_);
                }
            asm volatile("s_waitcnt lgkmcnt(0)" ::: "memory");

            // P A-frags: lane j=lh holds k=i = qd*8+jj (+32)
            short8 pf0 = *(const short8*)&Psh[wv][lh*64 + ((qd     ^ (lh & 7))*8)];
            short8 pf1 = *(const short8*)&Psh[wv][lh*64 + (((4+qd) ^ (lh & 7))*8)];

            // PV: o[j][d] += P·V, V B-frags from transposed LDS tile
            #pragma unroll
            for (int dt = 0; dt < 4; dt++) {
                const unsigned short* vr = Vb + (dt*16 + lh)*128;
                short8 v0 = *(const short8*)(vr + (((half*8 + qd    ) ^ lh)*8));
                short8 v1 = *(const short8*)(vr + (((half*8 + 4 + qd) ^ lh)*8));
                o_acc[dt] = __builtin_amdgcn_mfma_f32_16x16x32_bf16(pf0, v0, o_acc[dt], 0,0,0);
                o_acc[dt] = __builtin_amdgcn_mfma_f32_16x16x32_bf16(pf1, v1, o_acc[dt], 0,0,0);
            }
        }

        if (ck < 7) STOREC(p ^ 1);
        __syncthreads();
    }
#undef LOADC
#undef STOREC

    // reduce l over the 16 lh-lanes sharing each j-row
    float inv[4];
    #pragma unroll
    for (int r = 0; r < 4; r++) {
        float l = l_r[r];
        #pragma unroll
        for (int off = 1; off < 16; off <<= 1)
            l += __shfl_xor(l, off);
        l_r[r] = l;
        inv[r] = 1.0f / l;
    }
    const size_t pbase = ((size_t)(s*4 + b)*NN + j0);
    #pragma unroll
    for (int dt = 0; dt < 4; dt++)
        #pragma unroll
        for (int r = 0; r < 4; r++)
            Po16[(pbase + qd*4 + r)*64 + dt*16 + lh] = (_Float16)(o_acc[dt][r] * inv[r]);
    if (lh == 0) {
        #pragma unroll
        for (int r = 0; r < 4; r++)
            Pl[pbase + qd*4 + r] = l_r[r];
    }
}

// ---------------- Kernel 3: combine split-K partials -> sa16 ----------------
__global__ __launch_bounds__(256) void combine_kernel(
    const _Float16* __restrict__ Po16, const float* __restrict__ Pl,
    _Float16* __restrict__ sa16)
{
    int tid = blockIdx.x * 256 + threadIdx.x;    // 262144 threads
    int d4  = (tid & 15) * 4;
    int j   = (tid >> 4) & 4095;
    int b   = tid >> 16;
    float o0 = 0.f, o1 = 0.f, o2 = 0.f, o3 = 0.f, lsum = 0.f;
    #pragma unroll
    for (int s = 0; s < 4; s++) {
        size_t base = ((size_t)(s*4 + b)*NN + j);
        half4 v = *(const half4*)(Po16 + base*64 + d4);
        float l = Pl[base];
        o0 += l * (float)v[0]; o1 += l * (float)v[1];
        o2 += l * (float)v[2]; o3 += l * (float)v[3];
        lsum += l;
    }
    float inv = 1.0f / lsum;
    half4 r;
    r[0] = (_Float16)(o0 * inv); r[1] = (_Float16)(o1 * inv);
    r[2] = (_Float16)(o2 * inv); r[3] = (_Float16)(o3 * inv);
    *(half4*)(sa16 + ((size_t)b*NN + j)*64 + d4) = r;
}

// ---------------- Kernel 4: output projection + residual ----------------
// grid 512: (b, j-chunk of 32)
__global__ __launch_bounds__(256) void outproj_kernel(
    const _Float16* __restrict__ sa16, const _Float16* __restrict__ Wv16,
    const float* __restrict__ x, const float* __restrict__ gamma,
    float* __restrict__ out1, float* __restrict__ out2)
{
    const int t    = threadIdx.x;
    const int w    = t >> 6;
    const int lane = t & 63;
    const int lh   = lane & 15;
    const int qd   = lane >> 4;
    const int b    = blockIdx.x >> 7;
    const int j0   = (blockIdx.x & 127) << 5;
    const float g  = gamma[0];

    half8 sb[2][2];
    #pragma unroll
    for (int jt2 = 0; jt2 < 2; jt2++) {
        const size_t sbase = ((size_t)b*NN + j0 + jt2*16 + lh)*64 + qd*8;
        sb[jt2][0] = *(const half8*)(sa16 + sbase);
        sb[jt2][1] = *(const half8*)(sa16 + sbase + 32);
    }

    #pragma unroll 2
    for (int ot8 = 0; ot8 < 8; ot8++) {
        const int ot = w*8 + ot8;
        const size_t wbase = (size_t)(ot*16 + lh)*64 + qd*8;
        half8 a0 = *(const half8*)(Wv16 + wbase);
        half8 a1 = *(const half8*)(Wv16 + wbase + 32);
        #pragma unroll
        for (int jt2 = 0; jt2 < 2; jt2++) {
            f32x4 acc; acc[0]=0.f; acc[1]=0.f; acc[2]=0.f; acc[3]=0.f;
            acc = __builtin_amdgcn_mfma_f32_16x16x32_f16(a0, sb[jt2][0], acc, 0, 0, 0);
            acc = __builtin_amdgcn_mfma_f32_16x16x32_f16(a1, sb[jt2][1], acc, 0, 0, 0);
            const int jg = j0 + jt2*16 + lh;
            #pragma unroll
            for (int r = 0; r < 4; r++) {
                const int o = ot*16 + qd*4 + r;
                size_t idx = ((size_t)b*CC + o)*NN + jg;
                float v = acc[r];
                out2[idx] = v;
                out1[idx] = fmaf(g, v, x[idx]);
            }
        }
    }
}

extern "C" void kernel_launch(void* const* d_in, const int* in_sizes, int n_in,
                              void* d_out, int out_size, void* d_ws, size_t ws_size,
                              hipStream_t stream) {
    const float* x     = (const float*)d_in[0];
    const float* Wf    = (const float*)d_in[1];
    const float* Wg    = (const float*)d_in[2];
    const float* Wh    = (const float*)d_in[3];
    const float* Wv    = (const float*)d_in[4];
    const float* gamma = (const float*)d_in[5];

    float* out1 = (float*)d_out;
    float* out2 = out1 + (size_t)BB*CC*NN;

    const size_t BND = (size_t)BB*NN*64;   // 1M elements
    char* wp = (char*)d_ws;
    _Float16*       Kf   = (_Float16*)wp;        wp += BND*2;   // 2 MB (reused as sa16)
    _Float16*       Qf   = (_Float16*)wp;        wp += BND*2;   // 2 MB
    unsigned short* Vt   = (unsigned short*)wp;  wp += BND*2;   // 2 MB
    _Float16*       Po16 = (_Float16*)wp;        wp += BND*4*2; // 8 MB (4 splits)
    float*          Pl   = (float*)wp;           wp += (size_t)4*BB*NN*4;  // 256 KB
    _Float16*       Wc16 = (_Float16*)wp;        wp += (size_t)192*512*2;
    _Float16*       Wv16 = (_Float16*)wp;
    _Float16*       sa16 = Kf;   // alias: Kf dead after attn

    prep_kernel<<<dim3(64), dim3(256), 0, stream>>>(Wf, Wg, Wh, Wv, Wc16, Wv16);
    proj_kernel<<<dim3(BB*256), dim3(256), 0, stream>>>(x, Wc16, Kf, Qf, Vt);
    attn_kernel<<<dim3(BB*256), dim3(256), 0, stream>>>(Kf, Qf, Vt, Po16, Pl);
    combine_kernel<<<dim3(1024), dim3(256), 0, stream>>>(Po16, Pl, sa16);
    outproj_kernel<<<dim3(512), dim3(256), 0, stream>>>(sa16, Wv16, x, gamma, out1, out2);
}